// Round 5
// baseline (312.497 us; speedup 1.0000x reference)
//
#include <hip/hip_runtime.h>
#include <stdint.h>

// Ring attention == exact flash attention per (b,h) head over all G chunks.
// q,k,v: [G=4][B=2][H=16][S=1024][D=64] fp32.
//
// Round 10: rotated software pipeline (two S-tiles in flight).
//  - Model (calibrated vs round-9 counters): MFMA demand floor = 159k cyc/SIMD
//    (42% MfmaUtil at 154 us); the other ~58% is the serial QK->SM->PV chain
//    with barrier-phase-locked waves. Rotation: at iter t run QK(t+1) [MFMA]
//    then softmax(t) [VALU, independent] then PV(t) -- in-wave MFMA||VALU
//    overlap since the wave issues 16 independent QK MFMAs and executes exp2
//    VALU while the matrix pipe drains.
//  - Buffers: K double (K(t+2) -> slot t&1, last read by QK(t) pre-barrier),
//    V triple (stage (t+2)%3 never touches V(t)%3 being read). LDS 40 KB.
//  - Two live S-tile register sets (sA/sB), static roles via unroll-by-2.
//    __launch_bounds__(256,3): ~3 waves/SIMD == round-9's measured occupancy.
//  - All arithmetic bit-identical to round 9 (fp16 datapath, pi-permuted V,
//    fixed-reference softmax p=exp2(s), final 1/l normalization); zero-seed
//    folded into the first QK MFMA's C operand.

#define RG 4
#define RB 2
#define RH 16
#define RS 1024
#define RD 64

using bf16x8 = __attribute__((ext_vector_type(8))) short;
using bf16x4 = __attribute__((ext_vector_type(4))) short;
using f16x8  = __attribute__((ext_vector_type(8))) _Float16;
using f32x4  = __attribute__((ext_vector_type(4))) float;
using u32x2  = __attribute__((ext_vector_type(2))) uint32_t;
using u32x4  = __attribute__((ext_vector_type(4))) uint32_t;

#if __has_builtin(__builtin_amdgcn_mfma_f32_16x16x16_bf16)
#define MFMA_PV(a, b, c) __builtin_amdgcn_mfma_f32_16x16x16_bf16(a, b, c, 0, 0, 0)
#else
#define MFMA_PV(a, b, c) __builtin_amdgcn_mfma_f32_16x16x16bf16_1k(a, b, c, 0, 0, 0)
#endif

#if __has_builtin(__builtin_amdgcn_exp2f)
#define EXP2F(x) __builtin_amdgcn_exp2f(x)
#else
#define EXP2F(x) exp2f(x)
#endif

__device__ inline uint16_t f2bf(float x) {     // round-to-nearest-even bf16
    uint32_t u = __float_as_uint(x);
    u += 0x7fffu + ((u >> 16) & 1u);
    return (uint16_t)(u >> 16);
}
__device__ inline float bf2f(uint16_t b) {
    return __uint_as_float(((uint32_t)b) << 16);
}
// two fp32 -> packed bf16x2 (round-half-up)
__device__ inline uint32_t pkbf2(float lo, float hi) {
    uint32_t a = __float_as_uint(lo) + 0x8000u;
    uint32_t b = __float_as_uint(hi) + 0x8000u;
    return (a >> 16) | (b & 0xffff0000u);
}
// two fp32 -> packed fp16x2 (RTZ, single v_cvt_pkrtz_f16_f32)
__device__ inline uint32_t pkh2(float lo, float hi) {
#if __has_builtin(__builtin_amdgcn_cvt_pkrtz)
    return __builtin_bit_cast(uint32_t, __builtin_amdgcn_cvt_pkrtz(lo, hi));
#else
    union { _Float16 h[2]; uint32_t u; } r;
    r.h[0] = (_Float16)lo; r.h[1] = (_Float16)hi;
    return r.u;
#endif
}
__device__ inline uint4 pack8(const uint16_t* h) {
    uint4 r;
    r.x = (uint32_t)h[0] | ((uint32_t)h[1] << 16);
    r.y = (uint32_t)h[2] | ((uint32_t)h[3] << 16);
    r.z = (uint32_t)h[4] | ((uint32_t)h[5] << 16);
    r.w = (uint32_t)h[6] | ((uint32_t)h[7] << 16);
    return r;
}

// async global(16B/lane) -> LDS, linear layout: lds dest = lbase + lane*16B
__device__ inline void glds16(const uint16_t* g, uint16_t* lbase, int lane) {
#if __has_builtin(__builtin_amdgcn_global_load_lds)
    __builtin_amdgcn_global_load_lds(
        (const __attribute__((address_space(1))) uint32_t*)g,
        (__attribute__((address_space(3))) uint32_t*)lbase, 16, 0, 0);
#else
    *(uint4*)(lbase + lane * 8) = *(const uint4*)g;
#endif
}

// ===================== prepass: K,V -> fragment-linear fp16 =================
//
// Per 64-key tile (4096 fp16 = 8 KB each for K and V), output element order:
//   K-frag: seg = ks*256 + nt*64 + lane   (seg in [0,512), 8 elems per seg)
//           elem j: K[key = nt*16 + (lane&15)][d = ks*32 + (lane>>4)*8 + j]
//   V-frag: seg = dt*128 + b*64 + lane
//           elem j: V[key = b*32 + ((j>>2)<<4) + (lane>>4)*4 + (j&3)]
//                    [d   = dt*16 + (lane&15)]            (pi-permuted keys)
// Direct global gather (no LDS): K segs are 32B-contiguous per thread; V segs
// 2t and 2t+1 share the key set with adjacent d -> 8 float2 loads cover both.
__global__ __launch_bounds__(256)
void prep_kv(const float* __restrict__ k, const float* __restrict__ v,
             uint16_t* __restrict__ kf, uint16_t* __restrict__ vf) {
    const int bid = blockIdx.x;          // 128 head-chunks x 16 key-tiles
    const int t = threadIdx.x;
    const size_t base = (size_t)bid * (64 * RD);   // == (hc*16+kt)*4096

    {   // K-frags: thread t emits segs 2t, 2t+1 (adjacent keys, same d-range)
        uint4 o[2];
#pragma unroll
        for (int si = 0; si < 2; ++si) {
            const int s  = 2 * t + si;
            const int ks = s >> 8, nt = (s >> 6) & 3, ln = s & 63;
            const int key = nt * 16 + (ln & 15);
            const int d   = ks * 32 + (ln >> 4) * 8;
            const float* sp = k + base + (size_t)key * RD + d;
            float4 a0 = ((const float4*)sp)[0];
            float4 a1 = ((const float4*)sp)[1];
            o[si].x = pkh2(a0.x, a0.y); o[si].y = pkh2(a0.z, a0.w);
            o[si].z = pkh2(a1.x, a1.y); o[si].w = pkh2(a1.z, a1.w);
        }
        uint16_t* dst = kf + (size_t)bid * 4096 + t * 16;
        ((uint4*)dst)[0] = o[0]; ((uint4*)dst)[1] = o[1];
    }
    {   // V-frags (pi-permuted): segs 2t (d even) and 2t+1 (d+1) share keys
        const int s0 = 2 * t;
        const int dt = s0 >> 7, b = (s0 >> 6) & 1, ln = s0 & 63;
        const int c = ln & 15, qd = ln >> 4;
        const int d = dt * 16 + c;           // even -> float2 aligned
        float x0[8], x1[8];
#pragma unroll
        for (int j = 0; j < 8; ++j) {
            const int key = b * 32 + ((j >> 2) << 4) + qd * 4 + (j & 3);
            float2 xv = *(const float2*)(v + base + (size_t)key * RD + d);
            x0[j] = xv.x; x1[j] = xv.y;
        }
        uint4 o0, o1;
        o0.x = pkh2(x0[0], x0[1]); o0.y = pkh2(x0[2], x0[3]);
        o0.z = pkh2(x0[4], x0[5]); o0.w = pkh2(x0[6], x0[7]);
        o1.x = pkh2(x1[0], x1[1]); o1.y = pkh2(x1[2], x1[3]);
        o1.z = pkh2(x1[4], x1[5]); o1.w = pkh2(x1[6], x1[7]);
        uint16_t* dst = vf + (size_t)bid * 4096 + t * 16;
        ((uint4*)dst)[0] = o0; ((uint4*)dst)[1] = o1;
    }
}

// ===================== round-10 main kernel =================================
constexpr int TILE_SH = 4096;            // shorts per frag tile (K or V) = 8 KB
constexpr int NT      = (RG * RS) / 64;  // 64 key-tiles
// LDS layout (shorts): K slot0 @0, K slot1 @4096, V slots 0..2 @8192+...
constexpr int SMEM5   = 5 * TILE_SH;     // 40 KB

__global__ __launch_bounds__(256, 3)
void ring_attn_mfma7(const float* __restrict__ q, const uint16_t* __restrict__ kf_g,
                     const uint16_t* __restrict__ vf_g, float* __restrict__ out) {
    __shared__ __attribute__((aligned(16))) uint16_t smem[SMEM5];

    const int tid  = threadIdx.x;
    const int wave = tid >> 6;
    const int lane = tid & 63;
    const int quad = lane >> 4;
    const int col  = lane & 15;

    {   // deterministic LDS state on every launch
        uint32_t* sw = (uint32_t*)smem;
#pragma unroll
        for (int i = 0; i < SMEM5 / 2 / 256; ++i) sw[i * 256 + tid] = 0u;
    }
    __syncthreads();   // zero-init complete before staging

    const int bid   = blockIdx.x;
    const int head  = bid & 127;        // g*32 + b*16 + h ; bid%8 keeps head on one XCD
    const int qtile = bid >> 7;         // 0..7
    const int bh    = head & 31;        // b*16 + h

    const size_t hcq = (size_t)head * (RS * RD);
    const int qbase  = qtile * 128 + wave * 32;

    const float sc = 0.125f * 1.44269504088896340736f; // 1/sqrt(64) * log2(e)

    // stage key-tile `it` into K slot kslot (0/1) and V slot vslot (0..2)
    auto stage = [&](int it, int kslot, int vslot) {
        const size_t tb =
            (size_t)((((it >> 4) * 32 + bh) << 4) + (it & 15)) * TILE_SH;
        const uint16_t* gk = kf_g + tb;
        const uint16_t* gv = vf_g + tb;
        uint16_t* lk = smem + kslot * TILE_SH + wave * 512;
        uint16_t* lv = smem + (2 + vslot) * TILE_SH + wave * 512;
        glds16(gk + (size_t)tid * 8,         lk,        lane);
        glds16(gk + (size_t)(256 + tid) * 8, lk + 2048, lane);
        glds16(gv + (size_t)tid * 8,         lv,        lane);
        glds16(gv + (size_t)(256 + tid) * 8, lv + 2048, lane);
    };

    // ---- prologue: stage tiles 0,1 (async), load Q meanwhile ----
    stage(0, 0, 0);
    stage(1, 1, 1);

    f16x8 qf[2][2];                     // [mt][ks]
#pragma unroll
    for (int mt = 0; mt < 2; ++mt)
#pragma unroll
        for (int ks = 0; ks < 2; ++ks) {
            const float* qp = q + hcq + (size_t)(qbase + mt * 16 + col) * RD + ks * 32 + quad * 8;
            float4 t0 = ((const float4*)qp)[0];
            float4 t1 = ((const float4*)qp)[1];
            u32x4 w = {pkh2(t0.x * sc, t0.y * sc), pkh2(t0.z * sc, t0.w * sc),
                       pkh2(t1.x * sc, t1.y * sc), pkh2(t1.z * sc, t1.w * sc)};
            qf[mt][ks] = __builtin_bit_cast(f16x8, w);
        }

    f32x4 oacc[2][4];
#pragma unroll
    for (int mt = 0; mt < 2; ++mt)
#pragma unroll
        for (int dt = 0; dt < 4; ++dt) oacc[mt][dt] = (f32x4){0.f, 0.f, 0.f, 0.f};
    float lrun[2] = {0.f, 0.f};

    const f32x4 ZV = {0.f, 0.f, 0.f, 0.f};

    // S^T = K Q^T for the K-tile in `kbuf` -> sN (zero-seeded via ZV)
    auto qk_tile = [&](f32x4 (&sN)[2][4], const uint16_t* kbuf) {
#pragma unroll
        for (int nt = 0; nt < 4; ++nt) {
            f16x8 k0 = *(const f16x8*)&kbuf[(size_t)((0 * 4 + nt) * 64 + lane) * 8];
            f16x8 k1 = *(const f16x8*)&kbuf[(size_t)((1 * 4 + nt) * 64 + lane) * 8];
#pragma unroll
            for (int mt = 0; mt < 2; ++mt) {
                f32x4 acc = __builtin_amdgcn_mfma_f32_16x16x32_f16(k0, qf[mt][0], ZV, 0, 0, 0);
                sN[mt][nt] = __builtin_amdgcn_mfma_f32_16x16x32_f16(k1, qf[mt][1], acc, 0, 0, 0);
            }
        }
    };

    __syncthreads();                    // tiles 0,1 landed

    f32x4 sA[2][4], sB[2][4];
    qk_tile(sA, smem);                  // QK(0) from K slot 0
    __syncthreads();                    // all waves done reading K slot 0
                                        // (iter 0 stages K(2) into slot 0)

    // one pipelined iteration: consume sC (tile t), produce sN (tile t+1)
    auto run_iter = [&](int t, f32x4 (&sC)[2][4], f32x4 (&sN)[2][4], int vbt) {
        if (t + 2 < NT) {               // stage K(t+2)->slot t&1, V(t+2)->(vbt+2)%3
            int vs = vbt + 2; if (vs >= 3) vs -= 3;
            stage(t + 2, t & 1, vs);
        }
        if (t + 1 < NT) {               // QK(t+1) [MFMA] -- independent of softmax(t)
            __builtin_amdgcn_s_setprio(1);
            qk_tile(sN, smem + ((t + 1) & 1) * TILE_SH);
            __builtin_amdgcn_s_setprio(0);
        }

        // softmax(t) [VALU]: p = exp2(s); P packed per k32-block
        f16x8 pf[2][2];
#pragma unroll
        for (int mt = 0; mt < 2; ++mt) {
            float ls = 0.f;
            uint32_t w[4][2];
#pragma unroll
            for (int nt = 0; nt < 4; ++nt) {
                float p0 = EXP2F(sC[mt][nt][0]);
                float p1 = EXP2F(sC[mt][nt][1]);
                float p2 = EXP2F(sC[mt][nt][2]);
                float p3 = EXP2F(sC[mt][nt][3]);
                ls += (p0 + p1) + (p2 + p3);
                w[nt][0] = pkh2(p0, p1);
                w[nt][1] = pkh2(p2, p3);
            }
            u32x4 b0 = {w[0][0], w[0][1], w[1][0], w[1][1]};
            u32x4 b1 = {w[2][0], w[2][1], w[3][0], w[3][1]};
            pf[mt][0] = __builtin_bit_cast(f16x8, b0);
            pf[mt][1] = __builtin_bit_cast(f16x8, b1);
            lrun[mt] += ls;             // per-lane partial (this quad's keys)
        }

        // PV(t): O^T += V^T P^T over pi-permuted keys
        const uint16_t* vbuf = smem + (2 + vbt) * TILE_SH;
        __builtin_amdgcn_s_setprio(1);
#pragma unroll
        for (int dt = 0; dt < 4; ++dt)
#pragma unroll
            for (int b = 0; b < 2; ++b) {
                f16x8 vfr = *(const f16x8*)&vbuf[(size_t)((dt * 2 + b) * 64 + lane) * 8];
#pragma unroll
                for (int mt = 0; mt < 2; ++mt)
                    oacc[mt][dt] = __builtin_amdgcn_mfma_f32_16x16x32_f16(vfr, pf[mt][b], oacc[mt][dt], 0, 0, 0);
            }
        __builtin_amdgcn_s_setprio(0);

        __syncthreads();                // ONE barrier per tile; drains glds
    };

    int vb = 0;                         // V slot of tile t
    for (int t = 0; t < NT; t += 2) {   // static sA/sB roles (rule #20)
        run_iter(t,     sA, sB, vb); vb = (vb == 2) ? 0 : vb + 1;
        run_iter(t + 1, sB, sA, vb); vb = (vb == 2) ? 0 : vb + 1;
    }

    // ---- final: reduce l across quads, normalize, store ----
#pragma unroll
    for (int mt = 0; mt < 2; ++mt) {
        lrun[mt] += __shfl_xor(lrun[mt], 16);
        lrun[mt] += __shfl_xor(lrun[mt], 32);
        const float inv = 1.0f / lrun[mt];
        const int qrow = qbase + mt * 16 + col;
#pragma unroll
        for (int dt = 0; dt < 4; ++dt) {
            float4 st;
            st.x = oacc[mt][dt][0] * inv;
            st.y = oacc[mt][dt][1] * inv;
            st.z = oacc[mt][dt][2] * inv;
            st.w = oacc[mt][dt][3] * inv;
            *(float4*)&out[hcq + (size_t)qrow * RD + dt * 16 + quad * 4] = st;
        }
    }
}

// ------------- fallback pre-pass: V -> V^T (bf16, [G,B,H,D,S] layout) -------
__global__ __launch_bounds__(256)
void prep_vt(const float* __restrict__ v, uint16_t* __restrict__ vt) {
    __shared__ uint16_t tl[64 * 72];
    const int bid = blockIdx.x;          // 128 head-chunks x 16 key-tiles
    const int hc = bid >> 4, kt = bid & 15;
    const size_t base = (size_t)hc * (RS * RD);
    const int t = threadIdx.x;
    const int row = t >> 2;
    const int seg = (t & 3) * 16;

    const float* src = v + base + (size_t)(kt * 64 + row) * RD + seg;
    uint16_t hb[16];
#pragma unroll
    for (int i = 0; i < 4; ++i) {
        float4 x = ((const float4*)src)[i];
        hb[4 * i + 0] = f2bf(x.x); hb[4 * i + 1] = f2bf(x.y);
        hb[4 * i + 2] = f2bf(x.z); hb[4 * i + 3] = f2bf(x.w);
    }
    uint16_t* d = &tl[row * 72 + seg];
    ((uint4*)d)[0] = pack8(hb); ((uint4*)d)[1] = pack8(hb + 8);
    __syncthreads();

    uint16_t ob[16];
#pragma unroll
    for (int i = 0; i < 16; ++i) ob[i] = tl[(seg + i) * 72 + row]; // V^T[d=row][key]
    uint16_t* dst = vt + base + (size_t)row * RS + kt * 64 + seg;
    ((uint4*)dst)[0] = pack8(ob); ((uint4*)dst)[1] = pack8(ob + 8);
}

// --------------------- fallback: round-5 main kernel ------------------------
constexpr int KSTR   = 72;
constexpr int OFF_K  = 0;                // [64 key][72] bf16 (hi)
constexpr int OFF_VT = 64 * KSTR;        // [64 d][72 keys] bf16
constexpr int SMEM2  = 2 * 64 * KSTR;    // 9216 shorts = 18432 B

__global__ __launch_bounds__(256, 4)
void ring_attn_mfma3(const float* __restrict__ q, const float* __restrict__ k_g,
                     const uint16_t* __restrict__ vt_g, float* __restrict__ out) {
    __shared__ __attribute__((aligned(16))) uint16_t smem[SMEM2];

    const int tid  = threadIdx.x;
    const int wave = tid >> 6;
    const int lane = tid & 63;
    const int quad = lane >> 4;
    const int col  = lane & 15;

    {   // deterministic LDS state on every launch
        uint32_t* sw = (uint32_t*)smem;
#pragma unroll
        for (int i = 0; i < SMEM2 / 2 / 256; ++i) sw[i * 256 + tid] = 0u;
    }

    const int bid   = blockIdx.x;
    const int head  = bid & 127;
    const int qtile = bid >> 7;
    const int bh    = head & 31;

    const size_t hcq = (size_t)head * (RS * RD);
    const int qbase  = qtile * 128 + wave * 32;

    const float sc = 0.125f * 1.44269504088896340736f;

    bf16x8 qh[2][2], ql[2][2];
#pragma unroll
    for (int mt = 0; mt < 2; ++mt)
#pragma unroll
        for (int ks = 0; ks < 2; ++ks) {
            const float* qp = q + hcq + (size_t)(qbase + mt * 16 + col) * RD + ks * 32 + quad * 8;
            float4 t0 = ((const float4*)qp)[0];
            float4 t1 = ((const float4*)qp)[1];
            float xs[8] = {t0.x, t0.y, t0.z, t0.w, t1.x, t1.y, t1.z, t1.w};
            bf16x8 hv, lv;
#pragma unroll
            for (int j = 0; j < 8; ++j) {
                float x = xs[j] * sc;
                uint16_t hb = f2bf(x);
                hv[j] = (short)hb;
                lv[j] = (short)f2bf(x - bf2f(hb));
            }
            qh[mt][ks] = hv;
            ql[mt][ks] = lv;
        }

    f32x4 oacc[2][4];
#pragma unroll
    for (int mt = 0; mt < 2; ++mt)
#pragma unroll
        for (int dt = 0; dt < 4; ++dt) oacc[mt][dt] = (f32x4){0.f, 0.f, 0.f, 0.f};
    float lrun[2] = {0.f, 0.f};

    const int srow = tid >> 2;
    const int sseg = (tid & 3) * 16;

    for (int it = 0; it < (RG * RS) / 64; ++it) {
        const int gp = it >> 4, ktile = it & 15;
        const size_t cbase = (size_t)(gp * 32 + bh) * (RS * RD);

        __syncthreads();
        {
            const float* kp = k_g + cbase + (size_t)(ktile * 64 + srow) * RD + sseg;
            float4 a0 = ((const float4*)kp)[0];
            float4 a1 = ((const float4*)kp)[1];
            float4 a2 = ((const float4*)kp)[2];
            float4 a3 = ((const float4*)kp)[3];
            uint4 w0, w1;
            w0.x = pkbf2(a0.x, a0.y); w0.y = pkbf2(a0.z, a0.w);
            w0.z = pkbf2(a1.x, a1.y); w0.w = pkbf2(a1.z, a1.w);
            w1.x = pkbf2(a2.x, a2.y); w1.y = pkbf2(a2.z, a2.w);
            w1.z = pkbf2(a3.x, a3.y); w1.w = pkbf2(a3.z, a3.w);
            uint16_t* d0 = &smem[OFF_K + srow * KSTR + sseg];
            ((uint4*)d0)[0] = w0;
            ((uint4*)d0)[1] = w1;
            const uint16_t* s2 = vt_g + cbase + (size_t)srow * RS + ktile * 64 + sseg;
            uint16_t* d2 = &smem[OFF_VT + srow * KSTR + sseg];
            ((uint4*)d2)[0] = ((const uint4*)s2)[0];
            ((uint4*)d2)[1] = ((const uint4*)s2)[1];
        }
        __syncthreads();

        f32x4 sacc[2][4];
#pragma unroll
        for (int mt = 0; mt < 2; ++mt)
#pragma unroll
            for (int nt = 0; nt < 4; ++nt) sacc[mt][nt] = (f32x4){0.f, 0.f, 0.f, 0.f};
#pragma unroll
        for (int nt = 0; nt < 4; ++nt) {
            bf16x8 kf[2];
#pragma unroll
            for (int ks = 0; ks < 2; ++ks)
                kf[ks] = *(const bf16x8*)&smem[OFF_K + (nt * 16 + col) * KSTR + ks * 32 + quad * 8];
#pragma unroll
            for (int mt = 0; mt < 2; ++mt)
#pragma unroll
                for (int ks = 0; ks < 2; ++ks) {
                    sacc[mt][nt] = __builtin_amdgcn_mfma_f32_16x16x32_bf16(kf[ks], qh[mt][ks], sacc[mt][nt], 0, 0, 0);
                    sacc[mt][nt] = __builtin_amdgcn_mfma_f32_16x16x32_bf16(kf[ks], ql[mt][ks], sacc[mt][nt], 0, 0, 0);
                }
        }

        bf16x4 pf[2][4];
#pragma unroll
        for (int mt = 0; mt < 2; ++mt) {
            float ls = 0.f;
#pragma unroll
            for (int nt = 0; nt < 4; ++nt) {
                float p0 = EXP2F(sacc[mt][nt][0]);
                float p1 = EXP2F(sacc[mt][nt][1]);
                float p2 = EXP2F(sacc[mt][nt][2]);
                float p3 = EXP2F(sacc[mt][nt][3]);
                ls += (p0 + p1) + (p2 + p3);
                u32x2 t;
                t[0] = pkbf2(p0, p1);
                t[1] = pkbf2(p2, p3);
                pf[mt][nt] = __builtin_bit_cast(bf16x4, t);
            }
            lrun[mt] += ls;
        }

#pragma unroll
        for (int dt = 0; dt < 4; ++dt) {
            bf16x4 vf[4];
#pragma unroll
            for (int nt = 0; nt < 4; ++nt)
                vf[nt] = *(const bf16x4*)&smem[OFF_VT + (dt * 16 + col) * KSTR + nt * 16 + quad * 4];
#pragma unroll
            for (int mt = 0; mt < 2; ++mt)
#pragma unroll
                for (int nt = 0; nt < 4; ++nt)
                    oacc[mt][dt] = MFMA_PV(vf[nt], pf[mt][nt], oacc[mt][dt]);
        }
    }

#pragma unroll
    for (int mt = 0; mt < 2; ++mt) {
        lrun[mt] += __shfl_xor(lrun[mt], 16);
        lrun[mt] += __shfl_xor(lrun[mt], 32);
        const float inv = 1.0f / lrun[mt];
        const int qrow = qbase + mt * 16 + col;
#pragma unroll
        for (int dt = 0; dt < 4; ++dt) {
            float4 st;
            st.x = oacc[mt][dt][0] * inv;
            st.y = oacc[mt][dt][1] * inv;
            st.z = oacc[mt][dt][2] * inv;
            st.w = oacc[mt][dt][3] * inv;
            *(float4*)&out[hcq + (size_t)qrow * RD + dt * 16 + quad * 4] = st;
        }
    }
}

extern "C" void kernel_launch(void* const* d_in, const int* in_sizes, int n_in,
                              void* d_out, int out_size, void* d_ws, size_t ws_size,
                              hipStream_t stream) {
    const float* q = (const float*)d_in[0];
    const float* k = (const float*)d_in[1];
    const float* v = (const float*)d_in[2];
    float* out = (float*)d_out;

    const size_t NEL = (size_t)RG * RB * RH * RS * RD;   // 8,388,608
    const size_t need2 = 2 * NEL * sizeof(uint16_t);     // 33.6 MB (K-frag + V-frag)
    const size_t need1 = NEL * sizeof(uint16_t);         // 16.8 MB (V^T only)

    if (ws_size >= need2) {
        uint16_t* kf = (uint16_t*)d_ws;
        uint16_t* vf = kf + NEL;
        prep_kv<<<2048, 256, 0, stream>>>(k, v, kf, vf);
        ring_attn_mfma7<<<1024, 256, 0, stream>>>(q, kf, vf, out);
    } else if (ws_size >= need1) {
        uint16_t* vt = (uint16_t*)d_ws;
        prep_vt<<<2048, 256, 0, stream>>>(v, vt);
        ring_attn_mfma3<<<1024, 256, 0, stream>>>(q, k, vt, out);
    } else {
        uint16_t* vt = (uint16_t*)d_ws;  // best effort (not hit in harness)
        prep_vt<<<2048, 256, 0, stream>>>(v, vt);
        ring_attn_mfma3<<<1024, 256, 0, stream>>>(q, k, vt, out);
    }
}

// Round 6
// 262.679 us; speedup vs baseline: 1.1897x; 1.1897x over previous
//
#include <hip/hip_runtime.h>
#include <stdint.h>

// Ring attention == exact flash attention per (b,h) head over all G chunks.
// q,k,v: [G=4][B=2][H=16][S=1024][D=64] fp32.
//
// Round 11: round-9 structure + intra-tile half-split pipeline.
//  - ROUND-10 LESSON: 2-ahead prefetch + triple-V pushed per-XCD KV footprint
//    past the 4MB L2 (FETCH 36->59MB = the whole 50us regression), and
//    __syncthreads drains vmcnt(0) so >=2-ahead staging is useless anyway.
//    Reverted to 1-ahead, 32KB double buffer, one barrier per tile.
//  - Calibrated model: round-9 wall = MFMA demand (43%) + VALU demand (46%)
//    in ALTERNATION (sum 89% of wall) -- phase-locked waves. This round
//    splits each 64-key tile into halves A/B inside the iter:
//      QK-A, QK-B, SM-A, PV-A, SM-B, PV-B
//    SM-A (VALU) issues while QK-B drains the matrix pipe; SM-B issues while
//    PV-A drains -> in-wave MFMA||VALU overlap with zero structural change.
//  - Per-accumulator MFMA chain order unchanged -> bit-identical to round 9
//    except lrun summation order (fp32-benign). ZV-seeded QK drops the sacc
//    zero-init VALU.
//  - fp16 datapath, fragment-linear prepass, pi-permuted V, fixed-reference
//    softmax p = exp2(s) with final 1/l normalization, as rounds 8-9.

#define RG 4
#define RB 2
#define RH 16
#define RS 1024
#define RD 64

using bf16x8 = __attribute__((ext_vector_type(8))) short;
using bf16x4 = __attribute__((ext_vector_type(4))) short;
using f16x8  = __attribute__((ext_vector_type(8))) _Float16;
using f32x4  = __attribute__((ext_vector_type(4))) float;
using u32x2  = __attribute__((ext_vector_type(2))) uint32_t;
using u32x4  = __attribute__((ext_vector_type(4))) uint32_t;

#if __has_builtin(__builtin_amdgcn_mfma_f32_16x16x16_bf16)
#define MFMA_PV(a, b, c) __builtin_amdgcn_mfma_f32_16x16x16_bf16(a, b, c, 0, 0, 0)
#else
#define MFMA_PV(a, b, c) __builtin_amdgcn_mfma_f32_16x16x16bf16_1k(a, b, c, 0, 0, 0)
#endif

#if __has_builtin(__builtin_amdgcn_exp2f)
#define EXP2F(x) __builtin_amdgcn_exp2f(x)
#else
#define EXP2F(x) exp2f(x)
#endif

__device__ inline uint16_t f2bf(float x) {     // round-to-nearest-even bf16
    uint32_t u = __float_as_uint(x);
    u += 0x7fffu + ((u >> 16) & 1u);
    return (uint16_t)(u >> 16);
}
__device__ inline float bf2f(uint16_t b) {
    return __uint_as_float(((uint32_t)b) << 16);
}
// two fp32 -> packed bf16x2 (round-half-up)
__device__ inline uint32_t pkbf2(float lo, float hi) {
    uint32_t a = __float_as_uint(lo) + 0x8000u;
    uint32_t b = __float_as_uint(hi) + 0x8000u;
    return (a >> 16) | (b & 0xffff0000u);
}
// two fp32 -> packed fp16x2 (RTZ, single v_cvt_pkrtz_f16_f32)
__device__ inline uint32_t pkh2(float lo, float hi) {
#if __has_builtin(__builtin_amdgcn_cvt_pkrtz)
    return __builtin_bit_cast(uint32_t, __builtin_amdgcn_cvt_pkrtz(lo, hi));
#else
    union { _Float16 h[2]; uint32_t u; } r;
    r.h[0] = (_Float16)lo; r.h[1] = (_Float16)hi;
    return r.u;
#endif
}
__device__ inline uint4 pack8(const uint16_t* h) {
    uint4 r;
    r.x = (uint32_t)h[0] | ((uint32_t)h[1] << 16);
    r.y = (uint32_t)h[2] | ((uint32_t)h[3] << 16);
    r.z = (uint32_t)h[4] | ((uint32_t)h[5] << 16);
    r.w = (uint32_t)h[6] | ((uint32_t)h[7] << 16);
    return r;
}

// async global(16B/lane) -> LDS, linear layout: lds dest = lbase + lane*16B
__device__ inline void glds16(const uint16_t* g, uint16_t* lbase, int lane) {
#if __has_builtin(__builtin_amdgcn_global_load_lds)
    __builtin_amdgcn_global_load_lds(
        (const __attribute__((address_space(1))) uint32_t*)g,
        (__attribute__((address_space(3))) uint32_t*)lbase, 16, 0, 0);
#else
    *(uint4*)(lbase + lane * 8) = *(const uint4*)g;
#endif
}

// ===================== prepass: K,V -> fragment-linear fp16 =================
//
// Per 64-key tile (4096 fp16 = 8 KB each for K and V), output element order:
//   K-frag: seg = ks*256 + nt*64 + lane   (seg in [0,512), 8 elems per seg)
//           elem j: K[key = nt*16 + (lane&15)][d = ks*32 + (lane>>4)*8 + j]
//   V-frag: seg = dt*128 + b*64 + lane
//           elem j: V[key = b*32 + ((j>>2)<<4) + (lane>>4)*4 + (j&3)]
//                    [d   = dt*16 + (lane&15)]            (pi-permuted keys)
// Direct global gather (no LDS): K segs are 32B-contiguous per thread; V segs
// 2t and 2t+1 share the key set with adjacent d -> 8 float2 loads cover both.
__global__ __launch_bounds__(256)
void prep_kv(const float* __restrict__ k, const float* __restrict__ v,
             uint16_t* __restrict__ kf, uint16_t* __restrict__ vf) {
    const int bid = blockIdx.x;          // 128 head-chunks x 16 key-tiles
    const int t = threadIdx.x;
    const size_t base = (size_t)bid * (64 * RD);   // == (hc*16+kt)*4096

    {   // K-frags: thread t emits segs 2t, 2t+1 (adjacent keys, same d-range)
        uint4 o[2];
#pragma unroll
        for (int si = 0; si < 2; ++si) {
            const int s  = 2 * t + si;
            const int ks = s >> 8, nt = (s >> 6) & 3, ln = s & 63;
            const int key = nt * 16 + (ln & 15);
            const int d   = ks * 32 + (ln >> 4) * 8;
            const float* sp = k + base + (size_t)key * RD + d;
            float4 a0 = ((const float4*)sp)[0];
            float4 a1 = ((const float4*)sp)[1];
            o[si].x = pkh2(a0.x, a0.y); o[si].y = pkh2(a0.z, a0.w);
            o[si].z = pkh2(a1.x, a1.y); o[si].w = pkh2(a1.z, a1.w);
        }
        uint16_t* dst = kf + (size_t)bid * 4096 + t * 16;
        ((uint4*)dst)[0] = o[0]; ((uint4*)dst)[1] = o[1];
    }
    {   // V-frags (pi-permuted): segs 2t (d even) and 2t+1 (d+1) share keys
        const int s0 = 2 * t;
        const int dt = s0 >> 7, b = (s0 >> 6) & 1, ln = s0 & 63;
        const int c = ln & 15, qd = ln >> 4;
        const int d = dt * 16 + c;           // even -> float2 aligned
        float x0[8], x1[8];
#pragma unroll
        for (int j = 0; j < 8; ++j) {
            const int key = b * 32 + ((j >> 2) << 4) + qd * 4 + (j & 3);
            float2 xv = *(const float2*)(v + base + (size_t)key * RD + d);
            x0[j] = xv.x; x1[j] = xv.y;
        }
        uint4 o0, o1;
        o0.x = pkh2(x0[0], x0[1]); o0.y = pkh2(x0[2], x0[3]);
        o0.z = pkh2(x0[4], x0[5]); o0.w = pkh2(x0[6], x0[7]);
        o1.x = pkh2(x1[0], x1[1]); o1.y = pkh2(x1[2], x1[3]);
        o1.z = pkh2(x1[4], x1[5]); o1.w = pkh2(x1[6], x1[7]);
        uint16_t* dst = vf + (size_t)bid * 4096 + t * 16;
        ((uint4*)dst)[0] = o0; ((uint4*)dst)[1] = o1;
    }
}

// ===================== round-11 main kernel =================================
constexpr int TILE_SH = 4096;            // shorts per frag tile (K or V) = 8 KB
constexpr int BUF_SH  = 2 * TILE_SH;     // K+V buffer = 16 KB
constexpr int SMEM4   = 2 * BUF_SH;      // double-buffered = 32 KB
constexpr int NT      = (RG * RS) / 64;  // 64 key-tiles

// stage one 64-key tile (K+V) into LDS buffer dbuf via global_load_lds
__device__ inline void stage_tile(uint16_t* smem, const uint16_t* kf_g,
                                  const uint16_t* vf_g, size_t tb,
                                  int dbuf, int tid, int wave, int lane) {
    const uint16_t* gk = kf_g + tb;
    const uint16_t* gv = vf_g + tb;
    uint16_t* lk = smem + dbuf * BUF_SH + wave * 512;
    uint16_t* lv = smem + dbuf * BUF_SH + TILE_SH + wave * 512;
    glds16(gk + (size_t)tid * 8,         lk,        lane);
    glds16(gk + (size_t)(256 + tid) * 8, lk + 2048, lane);
    glds16(gv + (size_t)tid * 8,         lv,        lane);
    glds16(gv + (size_t)(256 + tid) * 8, lv + 2048, lane);
}

__global__ __launch_bounds__(256, 4)
void ring_attn_mfma8(const float* __restrict__ q, const uint16_t* __restrict__ kf_g,
                     const uint16_t* __restrict__ vf_g, float* __restrict__ out) {
    __shared__ __attribute__((aligned(16))) uint16_t smem[SMEM4];

    const int tid  = threadIdx.x;
    const int wave = tid >> 6;
    const int lane = tid & 63;
    const int quad = lane >> 4;
    const int col  = lane & 15;

    {   // deterministic LDS state on every launch
        uint32_t* sw = (uint32_t*)smem;
#pragma unroll
        for (int i = 0; i < SMEM4 / 2 / 256; ++i) sw[i * 256 + tid] = 0u;
    }
    __syncthreads();   // zero-init must complete before staging (round-7 fix)

    const int bid   = blockIdx.x;
    const int head  = bid & 127;        // g*32 + b*16 + h ; bid%8 keeps head on one XCD
    const int qtile = bid >> 7;         // 0..7
    const int bh    = head & 31;        // b*16 + h

    const size_t hcq = (size_t)head * (RS * RD);
    const int qbase  = qtile * 128 + wave * 32;

    const float sc = 0.125f * 1.44269504088896340736f; // 1/sqrt(64) * log2(e)

    // ---- prologue: stage tile 0 into buffer 0 (async, direct-to-LDS) ----
    stage_tile(smem, kf_g, vf_g, (size_t)(bh * 16) * TILE_SH, 0, tid, wave, lane);

    // ---- Q fragments (B-operand of S^T = K*Q^T): fp16, scaled, single-pass --
    // (loaded between stage-issue and barrier: global latency overlaps)
    f16x8 qf[2][2];                     // [mt][ks]
#pragma unroll
    for (int mt = 0; mt < 2; ++mt)
#pragma unroll
        for (int ks = 0; ks < 2; ++ks) {
            const float* qp = q + hcq + (size_t)(qbase + mt * 16 + col) * RD + ks * 32 + quad * 8;
            float4 t0 = ((const float4*)qp)[0];
            float4 t1 = ((const float4*)qp)[1];
            u32x4 w = {pkh2(t0.x * sc, t0.y * sc), pkh2(t0.z * sc, t0.w * sc),
                       pkh2(t1.x * sc, t1.y * sc), pkh2(t1.z * sc, t1.w * sc)};
            qf[mt][ks] = __builtin_bit_cast(f16x8, w);
        }

    // ---- accumulators: O^T tiles [mt][dt]; per-lane l partial ----
    f32x4 oacc[2][4];
#pragma unroll
    for (int mt = 0; mt < 2; ++mt)
#pragma unroll
        for (int dt = 0; dt < 4; ++dt) oacc[mt][dt] = (f32x4){0.f, 0.f, 0.f, 0.f};
    float lrun[2] = {0.f, 0.f};

    const f32x4 ZV = {0.f, 0.f, 0.f, 0.f};

    __syncthreads();                    // drains glds (tile 0 complete)

    int cur = 0;
    for (int it = 0; it < NT; ++it) {
        if (it + 1 < NT) {  // issue next-tile async loads into buf[cur^1]
            const int nit = it + 1;
            const size_t tb =
                (size_t)((((nit >> 4) * 32 + bh) << 4) + (nit & 15)) * TILE_SH;
            stage_tile(smem, kf_g, vf_g, tb, cur ^ 1, tid, wave, lane);
        }

        const uint16_t* kbuf = &smem[cur * BUF_SH];
        const uint16_t* vbuf = kbuf + TILE_SH;

        // ---- QK: S^T = K Q^T, half A (keys 0-31, nt 0,1) then half B ----
        f32x4 sacc[2][4];               // [mt][nt]; row=key quad*4+r, col=query
        __builtin_amdgcn_s_setprio(1);
#pragma unroll
        for (int nt = 0; nt < 4; ++nt) {
            f16x8 k0 = *(const f16x8*)&kbuf[(size_t)((0 * 4 + nt) * 64 + lane) * 8];
            f16x8 k1 = *(const f16x8*)&kbuf[(size_t)((1 * 4 + nt) * 64 + lane) * 8];
#pragma unroll
            for (int mt = 0; mt < 2; ++mt) {
                f32x4 acc = __builtin_amdgcn_mfma_f32_16x16x32_f16(k0, qf[mt][0], ZV, 0, 0, 0);
                sacc[mt][nt] = __builtin_amdgcn_mfma_f32_16x16x32_f16(k1, qf[mt][1], acc, 0, 0, 0);
            }
        }
        __builtin_amdgcn_s_setprio(0);

        // ---- SM-A (VALU; overlaps QK-B matrix-pipe drain): nt 0,1 -> pf[*][0]
        f16x8 pfA[2], pfB[2];
#pragma unroll
        for (int mt = 0; mt < 2; ++mt) {
            float p0 = EXP2F(sacc[mt][0][0]), p1 = EXP2F(sacc[mt][0][1]);
            float p2 = EXP2F(sacc[mt][0][2]), p3 = EXP2F(sacc[mt][0][3]);
            float p4 = EXP2F(sacc[mt][1][0]), p5 = EXP2F(sacc[mt][1][1]);
            float p6 = EXP2F(sacc[mt][1][2]), p7 = EXP2F(sacc[mt][1][3]);
            u32x4 bw = {pkh2(p0, p1), pkh2(p2, p3), pkh2(p4, p5), pkh2(p6, p7)};
            pfA[mt] = __builtin_bit_cast(f16x8, bw);
            lrun[mt] += ((p0 + p1) + (p2 + p3)) + ((p4 + p5) + (p6 + p7));
        }

        // ---- PV-A (MFMA): b=0 columns; per-(mt,dt) chain order == round 9 --
        __builtin_amdgcn_s_setprio(1);
#pragma unroll
        for (int dt = 0; dt < 4; ++dt) {
            f16x8 vfr = *(const f16x8*)&vbuf[(size_t)((dt * 2 + 0) * 64 + lane) * 8];
#pragma unroll
            for (int mt = 0; mt < 2; ++mt)
                oacc[mt][dt] = __builtin_amdgcn_mfma_f32_16x16x32_f16(vfr, pfA[mt], oacc[mt][dt], 0, 0, 0);
        }
        __builtin_amdgcn_s_setprio(0);

        // ---- SM-B (VALU; overlaps PV-A drain): nt 2,3 -> pf[*][1] ----
#pragma unroll
        for (int mt = 0; mt < 2; ++mt) {
            float p0 = EXP2F(sacc[mt][2][0]), p1 = EXP2F(sacc[mt][2][1]);
            float p2 = EXP2F(sacc[mt][2][2]), p3 = EXP2F(sacc[mt][2][3]);
            float p4 = EXP2F(sacc[mt][3][0]), p5 = EXP2F(sacc[mt][3][1]);
            float p6 = EXP2F(sacc[mt][3][2]), p7 = EXP2F(sacc[mt][3][3]);
            u32x4 bw = {pkh2(p0, p1), pkh2(p2, p3), pkh2(p4, p5), pkh2(p6, p7)};
            pfB[mt] = __builtin_bit_cast(f16x8, bw);
            lrun[mt] += ((p0 + p1) + (p2 + p3)) + ((p4 + p5) + (p6 + p7));
        }

        // ---- PV-B (MFMA): b=1 columns ----
        __builtin_amdgcn_s_setprio(1);
#pragma unroll
        for (int dt = 0; dt < 4; ++dt) {
            f16x8 vfr = *(const f16x8*)&vbuf[(size_t)((dt * 2 + 1) * 64 + lane) * 8];
#pragma unroll
            for (int mt = 0; mt < 2; ++mt)
                oacc[mt][dt] = __builtin_amdgcn_mfma_f32_16x16x32_f16(vfr, pfB[mt], oacc[mt][dt], 0, 0, 0);
        }
        __builtin_amdgcn_s_setprio(0);

        __syncthreads();                // ONE barrier per tile; drains glds
        cur ^= 1;
    }

    // ---- final: reduce l across quads, normalize, store ----
#pragma unroll
    for (int mt = 0; mt < 2; ++mt) {
        lrun[mt] += __shfl_xor(lrun[mt], 16);
        lrun[mt] += __shfl_xor(lrun[mt], 32);
        const float inv = 1.0f / lrun[mt];
        const int qrow = qbase + mt * 16 + col;
#pragma unroll
        for (int dt = 0; dt < 4; ++dt) {
            float4 st;
            st.x = oacc[mt][dt][0] * inv;
            st.y = oacc[mt][dt][1] * inv;
            st.z = oacc[mt][dt][2] * inv;
            st.w = oacc[mt][dt][3] * inv;
            *(float4*)&out[hcq + (size_t)qrow * RD + dt * 16 + quad * 4] = st;
        }
    }
}

// ------------- fallback pre-pass: V -> V^T (bf16, [G,B,H,D,S] layout) -------
__global__ __launch_bounds__(256)
void prep_vt(const float* __restrict__ v, uint16_t* __restrict__ vt) {
    __shared__ uint16_t tl[64 * 72];
    const int bid = blockIdx.x;          // 128 head-chunks x 16 key-tiles
    const int hc = bid >> 4, kt = bid & 15;
    const size_t base = (size_t)hc * (RS * RD);
    const int t = threadIdx.x;
    const int row = t >> 2;
    const int seg = (t & 3) * 16;

    const float* src = v + base + (size_t)(kt * 64 + row) * RD + seg;
    uint16_t hb[16];
#pragma unroll
    for (int i = 0; i < 4; ++i) {
        float4 x = ((const float4*)src)[i];
        hb[4 * i + 0] = f2bf(x.x); hb[4 * i + 1] = f2bf(x.y);
        hb[4 * i + 2] = f2bf(x.z); hb[4 * i + 3] = f2bf(x.w);
    }
    uint16_t* d = &tl[row * 72 + seg];
    ((uint4*)d)[0] = pack8(hb); ((uint4*)d)[1] = pack8(hb + 8);
    __syncthreads();

    uint16_t ob[16];
#pragma unroll
    for (int i = 0; i < 16; ++i) ob[i] = tl[(seg + i) * 72 + row]; // V^T[d=row][key]
    uint16_t* dst = vt + base + (size_t)row * RS + kt * 64 + seg;
    ((uint4*)dst)[0] = pack8(ob); ((uint4*)dst)[1] = pack8(ob + 8);
}

// --------------------- fallback: round-5 main kernel ------------------------
constexpr int KSTR   = 72;
constexpr int OFF_K  = 0;                // [64 key][72] bf16 (hi)
constexpr int OFF_VT = 64 * KSTR;        // [64 d][72 keys] bf16
constexpr int SMEM2  = 2 * 64 * KSTR;    // 9216 shorts = 18432 B

__global__ __launch_bounds__(256, 4)
void ring_attn_mfma3(const float* __restrict__ q, const float* __restrict__ k_g,
                     const uint16_t* __restrict__ vt_g, float* __restrict__ out) {
    __shared__ __attribute__((aligned(16))) uint16_t smem[SMEM2];

    const int tid  = threadIdx.x;
    const int wave = tid >> 6;
    const int lane = tid & 63;
    const int quad = lane >> 4;
    const int col  = lane & 15;

    {   // deterministic LDS state on every launch
        uint32_t* sw = (uint32_t*)smem;
#pragma unroll
        for (int i = 0; i < SMEM2 / 2 / 256; ++i) sw[i * 256 + tid] = 0u;
    }

    const int bid   = blockIdx.x;
    const int head  = bid & 127;
    const int qtile = bid >> 7;
    const int bh    = head & 31;

    const size_t hcq = (size_t)head * (RS * RD);
    const int qbase  = qtile * 128 + wave * 32;

    const float sc = 0.125f * 1.44269504088896340736f;

    bf16x8 qh[2][2], ql[2][2];
#pragma unroll
    for (int mt = 0; mt < 2; ++mt)
#pragma unroll
        for (int ks = 0; ks < 2; ++ks) {
            const float* qp = q + hcq + (size_t)(qbase + mt * 16 + col) * RD + ks * 32 + quad * 8;
            float4 t0 = ((const float4*)qp)[0];
            float4 t1 = ((const float4*)qp)[1];
            float xs[8] = {t0.x, t0.y, t0.z, t0.w, t1.x, t1.y, t1.z, t1.w};
            bf16x8 hv, lv;
#pragma unroll
            for (int j = 0; j < 8; ++j) {
                float x = xs[j] * sc;
                uint16_t hb = f2bf(x);
                hv[j] = (short)hb;
                lv[j] = (short)f2bf(x - bf2f(hb));
            }
            qh[mt][ks] = hv;
            ql[mt][ks] = lv;
        }

    f32x4 oacc[2][4];
#pragma unroll
    for (int mt = 0; mt < 2; ++mt)
#pragma unroll
        for (int dt = 0; dt < 4; ++dt) oacc[mt][dt] = (f32x4){0.f, 0.f, 0.f, 0.f};
    float lrun[2] = {0.f, 0.f};

    const int srow = tid >> 2;
    const int sseg = (tid & 3) * 16;

    for (int it = 0; it < (RG * RS) / 64; ++it) {
        const int gp = it >> 4, ktile = it & 15;
        const size_t cbase = (size_t)(gp * 32 + bh) * (RS * RD);

        __syncthreads();
        {
            const float* kp = k_g + cbase + (size_t)(ktile * 64 + srow) * RD + sseg;
            float4 a0 = ((const float4*)kp)[0];
            float4 a1 = ((const float4*)kp)[1];
            float4 a2 = ((const float4*)kp)[2];
            float4 a3 = ((const float4*)kp)[3];
            uint4 w0, w1;
            w0.x = pkbf2(a0.x, a0.y); w0.y = pkbf2(a0.z, a0.w);
            w0.z = pkbf2(a1.x, a1.y); w0.w = pkbf2(a1.z, a1.w);
            w1.x = pkbf2(a2.x, a2.y); w1.y = pkbf2(a2.z, a2.w);
            w1.z = pkbf2(a3.x, a3.y); w1.w = pkbf2(a3.z, a3.w);
            uint16_t* d0 = &smem[OFF_K + srow * KSTR + sseg];
            ((uint4*)d0)[0] = w0;
            ((uint4*)d0)[1] = w1;
            const uint16_t* s2 = vt_g + cbase + (size_t)srow * RS + ktile * 64 + sseg;
            uint16_t* d2 = &smem[OFF_VT + srow * KSTR + sseg];
            ((uint4*)d2)[0] = ((const uint4*)s2)[0];
            ((uint4*)d2)[1] = ((const uint4*)s2)[1];
        }
        __syncthreads();

        f32x4 sacc[2][4];
#pragma unroll
        for (int mt = 0; mt < 2; ++mt)
#pragma unroll
            for (int nt = 0; nt < 4; ++nt) sacc[mt][nt] = (f32x4){0.f, 0.f, 0.f, 0.f};
#pragma unroll
        for (int nt = 0; nt < 4; ++nt) {
            bf16x8 kf[2];
#pragma unroll
            for (int ks = 0; ks < 2; ++ks)
                kf[ks] = *(const bf16x8*)&smem[OFF_K + (nt * 16 + col) * KSTR + ks * 32 + quad * 8];
#pragma unroll
            for (int mt = 0; mt < 2; ++mt)
#pragma unroll
                for (int ks = 0; ks < 2; ++ks) {
                    sacc[mt][nt] = __builtin_amdgcn_mfma_f32_16x16x32_bf16(kf[ks], qh[mt][ks], sacc[mt][nt], 0, 0, 0);
                    sacc[mt][nt] = __builtin_amdgcn_mfma_f32_16x16x32_bf16(kf[ks], ql[mt][ks], sacc[mt][nt], 0, 0, 0);
                }
        }

        bf16x4 pf[2][4];
#pragma unroll
        for (int mt = 0; mt < 2; ++mt) {
            float ls = 0.f;
#pragma unroll
            for (int nt = 0; nt < 4; ++nt) {
                float p0 = EXP2F(sacc[mt][nt][0]);
                float p1 = EXP2F(sacc[mt][nt][1]);
                float p2 = EXP2F(sacc[mt][nt][2]);
                float p3 = EXP2F(sacc[mt][nt][3]);
                ls += (p0 + p1) + (p2 + p3);
                u32x2 t;
                t[0] = pkbf2(p0, p1);
                t[1] = pkbf2(p2, p3);
                pf[mt][nt] = __builtin_bit_cast(bf16x4, t);
            }
            lrun[mt] += ls;
        }

#pragma unroll
        for (int dt = 0; dt < 4; ++dt) {
            bf16x4 vf[4];
#pragma unroll
            for (int nt = 0; nt < 4; ++nt)
                vf[nt] = *(const bf16x4*)&smem[OFF_VT + (dt * 16 + col) * KSTR + nt * 16 + quad * 4];
#pragma unroll
            for (int mt = 0; mt < 2; ++mt)
#pragma unroll
                for (int nt = 0; nt < 4; ++nt)
                    oacc[mt][dt] = MFMA_PV(vf[nt], pf[mt][nt], oacc[mt][dt]);
        }
    }

#pragma unroll
    for (int mt = 0; mt < 2; ++mt) {
        lrun[mt] += __shfl_xor(lrun[mt], 16);
        lrun[mt] += __shfl_xor(lrun[mt], 32);
        const float inv = 1.0f / lrun[mt];
        const int qrow = qbase + mt * 16 + col;
#pragma unroll
        for (int dt = 0; dt < 4; ++dt) {
            float4 st;
            st.x = oacc[mt][dt][0] * inv;
            st.y = oacc[mt][dt][1] * inv;
            st.z = oacc[mt][dt][2] * inv;
            st.w = oacc[mt][dt][3] * inv;
            *(float4*)&out[hcq + (size_t)qrow * RD + dt * 16 + quad * 4] = st;
        }
    }
}

extern "C" void kernel_launch(void* const* d_in, const int* in_sizes, int n_in,
                              void* d_out, int out_size, void* d_ws, size_t ws_size,
                              hipStream_t stream) {
    const float* q = (const float*)d_in[0];
    const float* k = (const float*)d_in[1];
    const float* v = (const float*)d_in[2];
    float* out = (float*)d_out;

    const size_t NEL = (size_t)RG * RB * RH * RS * RD;   // 8,388,608
    const size_t need2 = 2 * NEL * sizeof(uint16_t);     // 33.6 MB (K-frag + V-frag)
    const size_t need1 = NEL * sizeof(uint16_t);         // 16.8 MB (V^T only)

    if (ws_size >= need2) {
        uint16_t* kf = (uint16_t*)d_ws;
        uint16_t* vf = kf + NEL;
        prep_kv<<<2048, 256, 0, stream>>>(k, v, kf, vf);
        ring_attn_mfma8<<<1024, 256, 0, stream>>>(q, kf, vf, out);
    } else if (ws_size >= need1) {
        uint16_t* vt = (uint16_t*)d_ws;
        prep_vt<<<2048, 256, 0, stream>>>(v, vt);
        ring_attn_mfma3<<<1024, 256, 0, stream>>>(q, k, vt, out);
    } else {
        uint16_t* vt = (uint16_t*)d_ws;  // best effort (not hit in harness)
        prep_vt<<<2048, 256, 0, stream>>>(v, vt);
        ring_attn_mfma3<<<1024, 256, 0, stream>>>(q, k, vt, out);
    }
}